// Round 13
// baseline (2219.350 us; speedup 1.0000x reference)
//
#include <hip/hip_runtime.h>
#include <hip/hip_bf16.h>
#include <stdint.h>

typedef unsigned short ushort_t;
typedef __attribute__((ext_vector_type(4))) float f32x4;
typedef __attribute__((ext_vector_type(8))) short short8;

#define T_TOK 32768
#define QL    1536
#define KVL   512
#define RD    64
#define NQ    3072     // 16 heads * 192
#define ROWW  2112     // qkv_lora row: 1536+512+64
#define HS    576      // 512+64

// 256^2 GEMM, BK=32 steps, 64KB LDS -> 2 blocks/CU (TLP overlap)
#define BM 256
#define BN 256
#define KS 32
#define NSTEP (QL / KS)    // 48 K-steps
#define MT (T_TOK / BM)    // 128
#define NT (NQ / BN)       // 12

#define ACONV_BLOCKS (T_TOK * 192 / 256)     // 24576
#define WQ_BLOCKS    ((NQ / 32) * (QL / 32)) // 4608
#define KVP_BLOCKS   (T_TOK / 4)             // 8192

// -ln(10000)/32 : inv_freq_i = exp(i * NLOG) = 10000^(-i/32)
#define NLOG (-0.28782313662425572f)

static __device__ __forceinline__ short f2bf(float x) {
  __hip_bfloat16 h = __float2bfloat16(x);
  return *reinterpret_cast<short*>(&h);
}

#define NTST(p, v) __builtin_nontemporal_store((v), (p))

// async global->LDS, 16B per lane; LDS dest = wave-uniform base + lane*16
#define GLOAD16(gp, lp)                                        \
  __builtin_amdgcn_global_load_lds(                            \
      (const __attribute__((address_space(1))) void*)(gp),     \
      (__attribute__((address_space(3))) void*)(lp), 16, 0, 0)

// ---- kv body shared by merged pre-pass and fallback kernel ----
static __device__ __forceinline__ void kv_body(
    int tok, int lane, const float* __restrict__ qkv, const int* __restrict__ pos,
    const int* __restrict__ slots, float* __restrict__ out_kvc,
    float* __restrict__ out_kpe, float* __restrict__ out_cache) {
  const float* src = qkv + (size_t)tok * ROWW + QL;   // kv_c (512) then k_pe (64)
  float* dkv = out_kvc + (size_t)tok * KVL;
  float* dc  = out_cache + (size_t)slots[tok] * HS;
#pragma unroll
  for (int i = 0; i < 2; ++i) {
    f32x4 v = *(const f32x4*)(src + (size_t)(lane + 64 * i) * 4);
    NTST((f32x4*)(dkv + (size_t)(lane + 64 * i) * 4), v);
    NTST((f32x4*)(dc + (size_t)(lane + 64 * i) * 4), v);
  }
  if (lane < 32) {
    float x1 = src[KVL + lane], x2 = src[KVL + 32 + lane];
    float p = (float)pos[tok];
    float invf = __expf((float)lane * NLOG);
    float s, c;
    __sincosf(p * invf, &s, &c);
    float r1 = x1 * c - x2 * s;
    float r2 = x2 * c + x1 * s;
    NTST(out_kpe + (size_t)tok * RD + lane, r1);
    NTST(out_kpe + (size_t)tok * RD + 32 + lane, r2);
    NTST(dc + KVL + lane, r1);
    NTST(dc + KVL + 32 + lane, r2);
  }
}

// ------- merged pre-pass: aconv + Wq transpose/convert + (optional) kv -------
__global__ __launch_bounds__(256) void pre_kernel(
    const float* __restrict__ qkv, ushort_t* __restrict__ Abf,
    const float* __restrict__ Wq, ushort_t* __restrict__ Wt,
    const int* __restrict__ pos, const int* __restrict__ slots,
    float* __restrict__ out_kvc, float* __restrict__ out_kpe,
    float* __restrict__ out_cache, int do_kv) {
  __shared__ float tile[32][33];
  int bid = blockIdx.x, tid = threadIdx.x;
  if (bid < ACONV_BLOCKS) {
    // q_c fp32 (strided rows) -> Abf bf16 [32768][1536]
    int g = bid * 256 + tid;                  // one 8-elem group per thread
    int row = g / 192;                        // 192 groups per row
    int col = (g - row * 192) * 8;
    const float* s = qkv + (size_t)row * ROWW + col;
    f32x4 a = *(const f32x4*)s;
    f32x4 b = *(const f32x4*)(s + 4);
    short8 v;
    v[0] = f2bf(a[0]); v[1] = f2bf(a[1]); v[2] = f2bf(a[2]); v[3] = f2bf(a[3]);
    v[4] = f2bf(b[0]); v[5] = f2bf(b[1]); v[6] = f2bf(b[2]); v[7] = f2bf(b[3]);
    *(short8*)(Abf + (size_t)row * QL + col) = v;
  } else if (bid < ACONV_BLOCKS + WQ_BLOCKS) {
    // Wq[1536][3072] f32 -> Wt[3072][1536] bf16
    int b2 = bid - ACONV_BLOCKS;
    int n0 = (b2 % (NQ / 32)) * 32, k0 = (b2 / (NQ / 32)) * 32;
    int tx = tid & 31, ty = tid >> 5;         // (32, 8)
#pragma unroll
    for (int j = 0; j < 32; j += 8)
      tile[ty + j][tx] = Wq[(size_t)(k0 + ty + j) * NQ + n0 + tx];
    __syncthreads();
#pragma unroll
    for (int j = 0; j < 32; j += 8)
      Wt[(size_t)(n0 + ty + j) * QL + k0 + tx] = f2bf(tile[tx][ty + j]);
  } else if (do_kv) {
    int b3 = bid - ACONV_BLOCKS - WQ_BLOCKS;
    int tok = b3 * 4 + (tid >> 6);
    kv_body(tok, tid & 63, qkv, pos, slots, out_kvc, out_kpe, out_cache);
  }
}

// ------ bf16 GEMM (Abf @ Wt^T): BK=32 steps, 64KB LDS, 2 blocks/CU + RoPE -----
// LDS: [par][A/B][256 x 32]; swizzle: 16B chunk c of row r holds global chunk
// c ^ ((r>>1)&3) (2-way bank alias = free; measured 0 conflicts at this map).
// Per step s (par=s&1), ONE __syncthreads (implicit vmcnt0+lgkm0 drain):
//   sync                     // step-s buffers staged; step s-1 reads retired
//   stage step s+1 -> par^1  // disjoint from all step-s reads
//   rd af0 x4 + bf x4 ; c0 (acc0-3) ; rd af1 x4 ; c1 (acc4-7)
// Overlap comes from the CO-RESIDENT BLOCK (2 blocks/CU): its waves fill this
// block's barrier drains and LDS windows (m114 TLP mechanism).
__global__ __launch_bounds__(512, 4) void gemm_rope_kernel(
    const ushort_t* __restrict__ Abf, const int* __restrict__ pos,
    const ushort_t* __restrict__ wt, float* __restrict__ out_q) {
  __shared__ ushort_t lds[2][2][256 * 32];   // 64 KiB -> 2 blocks/CU

  int bid = blockIdx.x;
  // XCD swizzle (1536 % 8 == 0 -> bijective): 192 consecutive vb per XCD
  int vb = (bid & 7) * (MT * NT / 8) + (bid >> 3);
  int m0 = (vb / NT) * BM;
  int n0 = (vb % NT) * BN;

  int tid = threadIdx.x;
  int wv = tid >> 6, ln = tid & 63;
  int l16 = ln & 15, lq4 = ln >> 4;
  int wm = wv >> 2, wn = wv & 3;          // 2x4 wave grid; wave owns 128x64 of C

  // ---- staging: wave wv covers rows [wv*32, wv*32+32); row = ln>>2, chunk=ln&3
  // inverse-swizzle source chunk by key (row>>1)&3 = (ln>>3)&3.
  int srow = wv * 32 + (ln >> 2);
  int schunk = ((ln & 3) ^ ((ln >> 3) & 3)) * 8;
  const ushort_t* aS = Abf + (size_t)(m0 + srow) * QL + schunk;
  const ushort_t* bS = wt  + (size_t)(n0 + srow) * QL + schunk;
  int sdst = wv * 32 * 32;                // elems; +512 for second instr

#define STG(PAR, SS) do {                                                      \
    GLOAD16(aS + (size_t)(SS) * KS,           &lds[PAR][0][sdst]);             \
    GLOAD16(aS + (size_t)(SS) * KS + 16 * QL, &lds[PAR][0][sdst + 512]);       \
    GLOAD16(bS + (size_t)(SS) * KS,           &lds[PAR][1][sdst]);             \
    GLOAD16(bS + (size_t)(SS) * KS + 16 * QL, &lds[PAR][1][sdst + 512]);       \
  } while (0)

  // ---- fragment read addressing (swizzled): key = (l16>>1)&3 ----
  int rkey = (l16 >> 1) & 3;
  int aoff = (wm * 128 + l16) * 32 + (lq4 ^ rkey) * 8;   // + mi*512
  int boff = (wn * 64  + l16) * 32 + (lq4 ^ rkey) * 8;   // + ni*512

  f32x4 acc[8][4];
#pragma unroll
  for (int i = 0; i < 8; ++i)
#pragma unroll
    for (int j = 0; j < 4; ++j) acc[i][j] = (f32x4)0.0f;

  // ---- prologue: stage step 0 ----
  STG(0, 0);

#define CLUSTER(ACCBASE, AF, BF)                                               \
  __builtin_amdgcn_s_setprio(1);                                               \
  _Pragma("unroll")                                                            \
  for (int q = 0; q < 4; ++q)                                                  \
    _Pragma("unroll")                                                          \
    for (int n = 0; n < 4; ++n)                                                \
      acc[(ACCBASE) + q][n] = __builtin_amdgcn_mfma_f32_16x16x32_bf16(         \
          AF[q], BF[n], acc[(ACCBASE) + q][n], 0, 0, 0);                       \
  __builtin_amdgcn_s_setprio(0);

#pragma unroll 2
  for (int s = 0; s < NSTEP; ++s) {
    int par = s & 1;
    const ushort_t* Ab = &lds[par][0][0];
    const ushort_t* Bb = &lds[par][1][0];
    short8 af0[4], af1[4], bf0[4];

    __syncthreads();   // step-s buffers landed; step s-1 reads retired

    // stage step s+1 into par^1 (disjoint from every step-s read)
    if (s + 1 < NSTEP) STG(par ^ 1, s + 1);

    // frag reads + 2 MFMA clusters
#pragma unroll
    for (int q = 0; q < 4; ++q) af0[q] = *(const short8*)(Ab + aoff + q * 512);
#pragma unroll
    for (int n = 0; n < 4; ++n) bf0[n] = *(const short8*)(Bb + boff + n * 512);
    CLUSTER(0, af0, bf0)
#pragma unroll
    for (int q = 0; q < 4; ++q) af1[q] = *(const short8*)(Ab + aoff + (4 + q) * 512);
    CLUSTER(4, af1, bf0)
  }

  // ---- epilogue: C/D layout col = lane&15, row = (lane>>4)*4 + reg ----
  // out_q write-once -> nontemporal (keeps L2 for A/B panels; R11-verified)
  int gn = n0 + wn * 64;
  bool ropew = ((gn % 192) == 128);        // rope region is 64-wide, 64-aligned
  if (!ropew) {
#pragma unroll
    for (int mi = 0; mi < 8; ++mi)
#pragma unroll
      for (int r = 0; r < 4; ++r) {
        int t = m0 + wm * 128 + mi * 16 + lq4 * 4 + r;
        float* rowp = out_q + (size_t)t * NQ + gn + l16;
        NTST(rowp + 0,  acc[mi][0][r]);
        NTST(rowp + 16, acc[mi][1][r]);
        NTST(rowp + 32, acc[mi][2][r]);
        NTST(rowp + 48, acc[mi][3][r]);
      }
  } else {
    float invf0 = __expf((float)l16 * NLOG);
    float invf1 = __expf((float)(l16 + 16) * NLOG);
#pragma unroll
    for (int mi = 0; mi < 8; ++mi)
#pragma unroll
      for (int r = 0; r < 4; ++r) {
        int t = m0 + wm * 128 + mi * 16 + lq4 * 4 + r;
        float p = (float)pos[t];
        float s0, c0, s1, c1;
        __sincosf(p * invf0, &s0, &c0);
        __sincosf(p * invf1, &s1, &c1);
        float x1a = acc[mi][0][r], x1b = acc[mi][1][r];
        float x2a = acc[mi][2][r], x2b = acc[mi][3][r];
        float* rowp = out_q + (size_t)t * NQ + gn + l16;
        NTST(rowp + 0,  x1a * c0 - x2a * s0);
        NTST(rowp + 16, x1b * c1 - x2b * s1);
        NTST(rowp + 32, x2a * c0 + x1a * s0);
        NTST(rowp + 48, x2b * c1 + x1b * s1);
      }
  }
}

// ---------------- standalone kv (alias-scratch fallback path) ----------------
__global__ void kv_kernel(const float* __restrict__ qkv, const int* __restrict__ pos,
                          const int* __restrict__ slots,
                          float* __restrict__ out_kvc, float* __restrict__ out_kpe,
                          float* __restrict__ out_cache) {
  int tok = blockIdx.x * 4 + (threadIdx.x >> 6);
  kv_body(tok, threadIdx.x & 63, qkv, pos, slots, out_kvc, out_kpe, out_cache);
}

extern "C" void kernel_launch(void* const* d_in, const int* in_sizes, int n_in,
                              void* d_out, int out_size, void* d_ws, size_t ws_size,
                              hipStream_t stream) {
  const float* qkv       = (const float*)d_in[0];
  const int*   positions = (const int*)d_in[1];
  const float* Wq        = (const float*)d_in[2];
  // d_in[3] = kv_cache input (fully overwritten: slot_mapping is a permutation)
  const int*   slots     = (const int*)d_in[4];

  float* out_q     = (float*)d_out;
  float* out_kvc   = out_q   + (size_t)T_TOK * NQ;
  float* out_kpe   = out_kvc + (size_t)T_TOK * KVL;
  float* out_cache = out_kpe + (size_t)T_TOK * RD;

  // scratch: Abf bf16 (100.7 MB) + Wt bf16 (9.4 MB).
  // Prefer d_ws (kv merges into pre-pass); else alias into out_kvc.. region —
  // then kv must run AFTER the GEMM (it overwrites the aliased Abf region).
  size_t abf_bytes = (size_t)T_TOK * QL * sizeof(ushort_t);   // 100,663,296
  size_t wt_bytes  = (size_t)NQ * QL * sizeof(ushort_t);      //   9,437,184
  int ws_ok = (ws_size >= abf_bytes + wt_bytes);
  char* scratch = ws_ok ? (char*)d_ws : (char*)out_kvc;
  ushort_t* Abf = (ushort_t*)scratch;
  ushort_t* Wt  = (ushort_t*)(scratch + abf_bytes);

  int pre_blocks = ACONV_BLOCKS + WQ_BLOCKS + (ws_ok ? KVP_BLOCKS : 0);
  pre_kernel<<<dim3(pre_blocks), dim3(256), 0, stream>>>(
      qkv, Abf, Wq, Wt, positions, slots, out_kvc, out_kpe, out_cache, ws_ok);
  gemm_rope_kernel<<<dim3(MT * NT), dim3(512), 0, stream>>>(Abf, positions, Wt, out_q);
  if (!ws_ok)
    kv_kernel<<<dim3(KVP_BLOCKS), dim3(256), 0, stream>>>(qkv, positions, slots,
                                                          out_kvc, out_kpe, out_cache);
}

// Round 14
// 415.639 us; speedup vs baseline: 5.3396x; 5.3396x over previous
//
#include <hip/hip_runtime.h>
#include <hip/hip_bf16.h>
#include <stdint.h>

typedef unsigned short ushort_t;
typedef __attribute__((ext_vector_type(4))) float f32x4;
typedef __attribute__((ext_vector_type(8))) short short8;

#define T_TOK 32768
#define QL    1536
#define KVL   512
#define RD    64
#define NQ    3072     // 16 heads * 192
#define ROWW  2112     // qkv_lora row: 1536+512+64
#define HS    576      // 512+64

// 256^2 counted-vmcnt GEMM (R4/R7 skeleton — best measured: 337us, 44% MfmaUtil)
#define BM 256
#define BN 256
#define BK 64
#define KT (QL / BK)       // 24 K-tiles
#define MT (T_TOK / BM)    // 128
#define NT (NQ / BN)       // 12

#define ACONV_BLOCKS (T_TOK * 192 / 256)     // 24576
#define WQ_BLOCKS    ((NQ / 32) * (QL / 32)) // 4608
#define KVP_BLOCKS   (T_TOK / 4)             // 8192

// -ln(10000)/32 : inv_freq_i = exp(i * NLOG) = 10000^(-i/32)
#define NLOG (-0.28782313662425572f)

static __device__ __forceinline__ short f2bf(float x) {
  __hip_bfloat16 h = __float2bfloat16(x);
  return *reinterpret_cast<short*>(&h);
}

#define NTST(p, v) __builtin_nontemporal_store((v), (p))

// async global->LDS, 16B per lane; LDS dest = wave-uniform base + lane*16
#define GLOAD16(gp, lp)                                        \
  __builtin_amdgcn_global_load_lds(                            \
      (const __attribute__((address_space(1))) void*)(gp),     \
      (__attribute__((address_space(3))) void*)(lp), 16, 0, 0)

// ---- kv body shared by merged pre-pass and fallback kernel ----
static __device__ __forceinline__ void kv_body(
    int tok, int lane, const float* __restrict__ qkv, const int* __restrict__ pos,
    const int* __restrict__ slots, float* __restrict__ out_kvc,
    float* __restrict__ out_kpe, float* __restrict__ out_cache) {
  const float* src = qkv + (size_t)tok * ROWW + QL;   // kv_c (512) then k_pe (64)
  float* dkv = out_kvc + (size_t)tok * KVL;
  float* dc  = out_cache + (size_t)slots[tok] * HS;
#pragma unroll
  for (int i = 0; i < 2; ++i) {
    f32x4 v = *(const f32x4*)(src + (size_t)(lane + 64 * i) * 4);
    NTST((f32x4*)(dkv + (size_t)(lane + 64 * i) * 4), v);
    NTST((f32x4*)(dc + (size_t)(lane + 64 * i) * 4), v);
  }
  if (lane < 32) {
    float x1 = src[KVL + lane], x2 = src[KVL + 32 + lane];
    float p = (float)pos[tok];
    float invf = __expf((float)lane * NLOG);
    float s, c;
    __sincosf(p * invf, &s, &c);
    float r1 = x1 * c - x2 * s;
    float r2 = x2 * c + x1 * s;
    NTST(out_kpe + (size_t)tok * RD + lane, r1);
    NTST(out_kpe + (size_t)tok * RD + 32 + lane, r2);
    NTST(dc + KVL + lane, r1);
    NTST(dc + KVL + 32 + lane, r2);
  }
}

// ------- merged pre-pass: aconv + Wq transpose/convert + (optional) kv -------
__global__ __launch_bounds__(256) void pre_kernel(
    const float* __restrict__ qkv, ushort_t* __restrict__ Abf,
    const float* __restrict__ Wq, ushort_t* __restrict__ Wt,
    const int* __restrict__ pos, const int* __restrict__ slots,
    float* __restrict__ out_kvc, float* __restrict__ out_kpe,
    float* __restrict__ out_cache, int do_kv) {
  __shared__ float tile[32][33];
  int bid = blockIdx.x, tid = threadIdx.x;
  if (bid < ACONV_BLOCKS) {
    // q_c fp32 (strided rows) -> Abf bf16 [32768][1536]  (re-read: keep cached)
    int g = bid * 256 + tid;                  // one 8-elem group per thread
    int row = g / 192;                        // 192 groups per row
    int col = (g - row * 192) * 8;
    const float* s = qkv + (size_t)row * ROWW + col;
    f32x4 a = *(const f32x4*)s;
    f32x4 b = *(const f32x4*)(s + 4);
    short8 v;
    v[0] = f2bf(a[0]); v[1] = f2bf(a[1]); v[2] = f2bf(a[2]); v[3] = f2bf(a[3]);
    v[4] = f2bf(b[0]); v[5] = f2bf(b[1]); v[6] = f2bf(b[2]); v[7] = f2bf(b[3]);
    *(short8*)(Abf + (size_t)row * QL + col) = v;
  } else if (bid < ACONV_BLOCKS + WQ_BLOCKS) {
    // Wq[1536][3072] f32 -> Wt[3072][1536] bf16  (re-read: keep cached)
    int b2 = bid - ACONV_BLOCKS;
    int n0 = (b2 % (NQ / 32)) * 32, k0 = (b2 / (NQ / 32)) * 32;
    int tx = tid & 31, ty = tid >> 5;         // (32, 8)
#pragma unroll
    for (int j = 0; j < 32; j += 8)
      tile[ty + j][tx] = Wq[(size_t)(k0 + ty + j) * NQ + n0 + tx];
    __syncthreads();
#pragma unroll
    for (int j = 0; j < 32; j += 8)
      Wt[(size_t)(n0 + ty + j) * QL + k0 + tx] = f2bf(tile[tx][ty + j]);
  } else if (do_kv) {
    int b3 = bid - ACONV_BLOCKS - WQ_BLOCKS;
    int tok = b3 * 4 + (tid >> 6);
    kv_body(tok, tid & 63, qkv, pos, slots, out_kvc, out_kpe, out_cache);
  }
}

// ---------------- bf16 GEMM (Abf @ Wt^T), R7 schedule + RoPE epilogue ----------
// LDS: [par][A/B][khalf][256 x 32]; swizzle: chunk c of row r holds global
// chunk c ^ ((r>>1)&3) (2-way bank alias = free; measured 0 conflicts).
// Per tile t (par=t&1), 2 barriers, 1 counted vmcnt:
//   [schedbar; vmcnt(4|0); s_barrier; schedbar]
//   r0: af0 x4 + bf x4 (K0);  r1: af1 x4
//   stage A/B-K1(t+1)
//   c0 (af0*bf), c1 (af1*bf)
//   r2: ag0 x4 + bg x4 (K1);  r3: ag1 x4
//   [schedbar; s_barrier; schedbar]
//   stage A/B-K0(t+2)
//   c2 (ag0*bg), c3 (ag1*bg)
// vmcnt audit: boundary outstanding = K0(t),K1(t),K0(t+1) = 12 -> vmcnt(4).
// NOTE (R12 lesson): acc = 128 VGPR/wave -> min-waves/EU must stay 2; any
// higher occupancy bound spills acc to scratch (10.7 GB HBM, 6% MfmaUtil).
__global__ __launch_bounds__(512, 2) void gemm_rope_kernel(
    const ushort_t* __restrict__ Abf, const int* __restrict__ pos,
    const ushort_t* __restrict__ wt, float* __restrict__ out_q) {
  __shared__ ushort_t lds[2][2][2][256 * 32];   // 128 KiB

  int bid = blockIdx.x;
  // XCD swizzle (1536 % 8 == 0 -> bijective): 192 consecutive vb per XCD
  int vb = (bid & 7) * (MT * NT / 8) + (bid >> 3);
  int m0 = (vb / NT) * BM;
  int n0 = (vb % NT) * BN;

  int tid = threadIdx.x;
  int wv = tid >> 6, ln = tid & 63;
  int l16 = ln & 15, lq4 = ln >> 4;
  int wm = wv >> 2, wn = wv & 3;          // 2x4 wave grid; wave owns 128x64 of C

  // ---- staging: wave wv covers rows [wv*32, wv*32+32); row = ln>>2, chunk=ln&3
  // inverse-swizzle source chunk by key (row>>1)&3 = (ln>>3)&3.
  int srow = wv * 32 + (ln >> 2);
  int schunk = ((ln & 3) ^ ((ln >> 3) & 3)) * 8;
  const ushort_t* aS = Abf + (size_t)(m0 + srow) * QL + schunk;
  const ushort_t* bS = wt  + (size_t)(n0 + srow) * QL + schunk;
  int sdst = wv * 32 * 32;                // elems; +512 for second instr

#define STG(PAR, AB, KH, TT, SRC) do {                                         \
    GLOAD16((SRC) + (size_t)(TT) * BK + (KH) * 32,           &lds[PAR][AB][KH][sdst]);       \
    GLOAD16((SRC) + (size_t)(TT) * BK + (KH) * 32 + 16 * QL, &lds[PAR][AB][KH][sdst + 512]); \
  } while (0)

  // ---- fragment read addressing (swizzled): key = (l16>>1)&3 ----
  int rkey = (l16 >> 1) & 3;
  int aoff = (wm * 128 + l16) * 32 + (lq4 ^ rkey) * 8;   // + mi*512
  int boff = (wn * 64  + l16) * 32 + (lq4 ^ rkey) * 8;   // + ni*512

  f32x4 acc[8][4];
#pragma unroll
  for (int i = 0; i < 8; ++i)
#pragma unroll
    for (int j = 0; j < 4; ++j) acc[i][j] = (f32x4)0.0f;

  // ---- prologue: K0(0), K1(0), K0(1) = 12 loads ----
  STG(0, 0, 0, 0, aS);   // A-K0(0)
  STG(0, 1, 0, 0, bS);   // B-K0(0)
  STG(0, 0, 1, 0, aS);   // A-K1(0)
  STG(0, 1, 1, 0, bS);   // B-K1(0)
  STG(1, 0, 0, 1, aS);   // A-K0(1)
  STG(1, 1, 0, 1, bS);   // B-K0(1)

#define CLUSTER(ACCBASE, AF, BF)                                               \
  __builtin_amdgcn_s_setprio(1);                                               \
  _Pragma("unroll")                                                            \
  for (int q = 0; q < 4; ++q)                                                  \
    _Pragma("unroll")                                                          \
    for (int n = 0; n < 4; ++n)                                                \
      acc[(ACCBASE) + q][n] = __builtin_amdgcn_mfma_f32_16x16x32_bf16(         \
          AF[q], BF[n], acc[(ACCBASE) + q][n], 0, 0, 0);                       \
  __builtin_amdgcn_s_setprio(0);

#pragma unroll 2
  for (int t = 0; t < KT; ++t) {
    int par = t & 1;
    const ushort_t* Ak0 = &lds[par][0][0][0];
    const ushort_t* Bk0 = &lds[par][1][0][0];
    const ushort_t* Ak1 = &lds[par][0][1][0];
    const ushort_t* Bk1 = &lds[par][1][1][0];
    short8 af0[4], af1[4], bf0[4], ag0[4], ag1[4], bg0[4];

    // ---- tile boundary ----
    __builtin_amdgcn_sched_barrier(0);
    if (t == KT - 1) { asm volatile("s_waitcnt vmcnt(0)" ::: "memory"); }
    else             { asm volatile("s_waitcnt vmcnt(4)" ::: "memory"); }
    __builtin_amdgcn_s_barrier();
    __builtin_amdgcn_sched_barrier(0);

    // r0 + r1 (K0 of tile t)
#pragma unroll
    for (int q = 0; q < 4; ++q) af0[q] = *(const short8*)(Ak0 + aoff + q * 512);
#pragma unroll
    for (int n = 0; n < 4; ++n) bf0[n] = *(const short8*)(Bk0 + boff + n * 512);
#pragma unroll
    for (int q = 0; q < 4; ++q) af1[q] = *(const short8*)(Ak0 + aoff + (4 + q) * 512);
    // stage K1(t+1): region last read at tile t-1, safe since boundary barrier
    if (t + 1 < KT) { STG(par ^ 1, 0, 1, t + 1, aS); STG(par ^ 1, 1, 1, t + 1, bS); }

    CLUSTER(0, af0, bf0)     // waits own r0 regs; r1 drains underneath
    CLUSTER(4, af1, bf0)

    // r2 + r3 (K1 of tile t) — valid since boundary; drain under c1/barrier
#pragma unroll
    for (int q = 0; q < 4; ++q) ag0[q] = *(const short8*)(Ak1 + aoff + q * 512);
#pragma unroll
    for (int n = 0; n < 4; ++n) bg0[n] = *(const short8*)(Bk1 + boff + n * 512);
#pragma unroll
    for (int q = 0; q < 4; ++q) ag1[q] = *(const short8*)(Ak1 + aoff + (4 + q) * 512);

    // mid barrier: c0/c1 operand waits imply all K0(t) reads complete (DS
    // in-order); barrier makes it block-wide -> K0 region restageable
    __builtin_amdgcn_sched_barrier(0);
    __builtin_amdgcn_s_barrier();
    __builtin_amdgcn_sched_barrier(0);
    if (t + 2 < KT) { STG(par, 0, 0, t + 2, aS); STG(par, 1, 0, t + 2, bS); }

    CLUSTER(0, ag0, bg0)
    CLUSTER(4, ag1, bg0)
  }

  // ---- epilogue: C/D layout col = lane&15, row = (lane>>4)*4 + reg ----
  // out_q is write-once, never re-read -> nontemporal (keep L2 for A/B panels)
  int gn = n0 + wn * 64;
  bool ropew = ((gn % 192) == 128);        // rope region is 64-wide, 64-aligned
  if (!ropew) {
#pragma unroll
    for (int mi = 0; mi < 8; ++mi)
#pragma unroll
      for (int r = 0; r < 4; ++r) {
        int t = m0 + wm * 128 + mi * 16 + lq4 * 4 + r;
        float* rowp = out_q + (size_t)t * NQ + gn + l16;
        NTST(rowp + 0,  acc[mi][0][r]);
        NTST(rowp + 16, acc[mi][1][r]);
        NTST(rowp + 32, acc[mi][2][r]);
        NTST(rowp + 48, acc[mi][3][r]);
      }
  } else {
    float invf0 = __expf((float)l16 * NLOG);
    float invf1 = __expf((float)(l16 + 16) * NLOG);
#pragma unroll
    for (int mi = 0; mi < 8; ++mi)
#pragma unroll
      for (int r = 0; r < 4; ++r) {
        int t = m0 + wm * 128 + mi * 16 + lq4 * 4 + r;
        float p = (float)pos[t];
        float s0, c0, s1, c1;
        __sincosf(p * invf0, &s0, &c0);
        __sincosf(p * invf1, &s1, &c1);
        float x1a = acc[mi][0][r], x1b = acc[mi][1][r];
        float x2a = acc[mi][2][r], x2b = acc[mi][3][r];
        float* rowp = out_q + (size_t)t * NQ + gn + l16;
        NTST(rowp + 0,  x1a * c0 - x2a * s0);
        NTST(rowp + 16, x1b * c1 - x2b * s1);
        NTST(rowp + 32, x2a * c0 + x1a * s0);
        NTST(rowp + 48, x2b * c1 + x1b * s1);
      }
  }
}

// ---------------- standalone kv (alias-scratch fallback path) ----------------
__global__ void kv_kernel(const float* __restrict__ qkv, const int* __restrict__ pos,
                          const int* __restrict__ slots,
                          float* __restrict__ out_kvc, float* __restrict__ out_kpe,
                          float* __restrict__ out_cache) {
  int tok = blockIdx.x * 4 + (threadIdx.x >> 6);
  kv_body(tok, threadIdx.x & 63, qkv, pos, slots, out_kvc, out_kpe, out_cache);
}

extern "C" void kernel_launch(void* const* d_in, const int* in_sizes, int n_in,
                              void* d_out, int out_size, void* d_ws, size_t ws_size,
                              hipStream_t stream) {
  const float* qkv       = (const float*)d_in[0];
  const int*   positions = (const int*)d_in[1];
  const float* Wq        = (const float*)d_in[2];
  // d_in[3] = kv_cache input (fully overwritten: slot_mapping is a permutation)
  const int*   slots     = (const int*)d_in[4];

  float* out_q     = (float*)d_out;
  float* out_kvc   = out_q   + (size_t)T_TOK * NQ;
  float* out_kpe   = out_kvc + (size_t)T_TOK * KVL;
  float* out_cache = out_kpe + (size_t)T_TOK * RD;

  // scratch: Abf bf16 (100.7 MB) + Wt bf16 (9.4 MB).
  // Prefer d_ws (kv merges into pre-pass); else alias into out_kvc.. region —
  // then kv must run AFTER the GEMM (it overwrites the aliased Abf region).
  size_t abf_bytes = (size_t)T_TOK * QL * sizeof(ushort_t);   // 100,663,296
  size_t wt_bytes  = (size_t)NQ * QL * sizeof(ushort_t);      //   9,437,184
  int ws_ok = (ws_size >= abf_bytes + wt_bytes);
  char* scratch = ws_ok ? (char*)d_ws : (char*)out_kvc;
  ushort_t* Abf = (ushort_t*)scratch;
  ushort_t* Wt  = (ushort_t*)(scratch + abf_bytes);

  int pre_blocks = ACONV_BLOCKS + WQ_BLOCKS + (ws_ok ? KVP_BLOCKS : 0);
  pre_kernel<<<dim3(pre_blocks), dim3(256), 0, stream>>>(
      qkv, Abf, Wq, Wt, positions, slots, out_kvc, out_kpe, out_cache, ws_ok);
  gemm_rope_kernel<<<dim3(MT * NT), dim3(512), 0, stream>>>(Abf, positions, Wt, out_q);
  if (!ws_ok)
    kv_kernel<<<dim3(KVP_BLOCKS), dim3(256), 0, stream>>>(qkv, positions, slots,
                                                          out_kvc, out_kpe, out_cache);
}